// Round 9
// baseline (146.135 us; speedup 1.0000x reference)
//
#include <hip/hip_runtime.h>
#include <math.h>

#define BB 4
#define CC 256
#define NN 4096
#define KK 32
#define DD 256
#define GG 8    // C/K
#define NT2 64  // n-tiles of 64 in k_dist
#define NE 8    // n-eighths in the two GEMM kernels
#define XPT_BLOCKS (BB * 32 * NE)  // 1024
#define EPI (BB * KK)              // 128 epilogue units

__device__ __forceinline__ float wredsum(float v) {
#pragma unroll
  for (int o = 32; o > 0; o >>= 1) v += __shfl_xor(v, o, 64);
  return v;
}

// Kernel 1: phi = exp(grouped conv) unnormalized + Sp half-partials.
// Also resets the two arrival counters (runs strictly before their users).
// grid = B*K*2 halves = 256, block 256. phi layout [b][k][n].
__global__ __launch_bounds__(256) void k_phi(const float* __restrict__ x,
                                             const float* __restrict__ wphi,
                                             float* __restrict__ phi,
                                             float* __restrict__ Sp,
                                             int* __restrict__ cnts) {
  const int tid = threadIdx.x;
  if (blockIdx.x == 0 && tid == 0) {
    __hip_atomic_store(&cnts[0], 0, __ATOMIC_RELAXED, __HIP_MEMORY_SCOPE_AGENT);
    __hip_atomic_store(&cnts[1], 0, __ATOMIC_RELAXED, __HIP_MEMORY_SCOPE_AGENT);
  }
  const int half = blockIdx.x & 1;
  const int k = (blockIdx.x >> 1) & 31;
  const int b = blockIdx.x >> 6;
  const float* xb = x + (size_t)(b * CC + k * GG) * NN + half * 2048;
  float w[GG];
#pragma unroll
  for (int j = 0; j < GG; ++j) w[j] = wphi[k * GG + j];
  float4 v[2];
  float sum = 0.f;
#pragma unroll
  for (int i = 0; i < 2; ++i) {
    const int n = i * 1024 + tid * 4;
    float4 s = make_float4(0.f, 0.f, 0.f, 0.f);
#pragma unroll
    for (int j = 0; j < GG; ++j) {
      const float4 xv = *reinterpret_cast<const float4*>(xb + (size_t)j * NN + n);
      s.x = fmaf(xv.x, w[j], s.x);
      s.y = fmaf(xv.y, w[j], s.y);
      s.z = fmaf(xv.z, w[j], s.z);
      s.w = fmaf(xv.w, w[j], s.w);
    }
    v[i].x = __expf(s.x);
    v[i].y = __expf(s.y);
    v[i].z = __expf(s.z);
    v[i].w = __expf(s.w);
    sum += v[i].x + v[i].y + v[i].z + v[i].w;
  }
  float* pk = phi + (size_t)(b * KK + k) * NN + half * 2048;
#pragma unroll
  for (int i = 0; i < 2; ++i) {
    *reinterpret_cast<float4*>(pk + i * 1024 + tid * 4) = v[i];
  }
  __shared__ float rb[4];
  sum = wredsum(sum);
  if ((tid & 63) == 0) rb[tid >> 6] = sum;
  __syncthreads();
  if (tid == 0)
    Sp[((size_t)half * BB + b) * KK + k] = rb[0] + rb[1] + rb[2] + rb[3];
}

// Kernel 2: m1 partials (round-5 k_xpT body) + fused k_code epilogue.
// grid = 1024 blocks, block 256. m1e layout [e][b][k][c].
// Last 128 arrivals each run the k_code body for one (b,k).
__global__ __launch_bounds__(256) void k_xpT_code(
    const float* __restrict__ x, const float* __restrict__ phi,
    float* __restrict__ m1e, const float* __restrict__ Sp,
    const float* __restrict__ wth, const float* __restrict__ scale,
    float* __restrict__ code, float* __restrict__ bc2,
    float* __restrict__ s2g, float* __restrict__ t3, int* __restrict__ cnt) {
  const int e = blockIdx.x & 7;
  const int ct = (blockIdx.x >> 3) & 31;
  const int b = blockIdx.x >> 8;
  const int tid = threadIdx.x;
  __shared__ float smem[256 * 33];
  const int kl = tid >> 3;  // stage: phi row (k)
  const int nq = tid & 7;
  const int k = tid & 31;   // compute: k lane
  const int g = tid >> 5;   // compute: n-group
  const float* xb = x + (size_t)(b * CC + ct * 8) * NN + e * 512;
  float acc[8] = {0.f, 0.f, 0.f, 0.f, 0.f, 0.f, 0.f, 0.f};
#pragma unroll
  for (int ch = 0; ch < 2; ++ch) {
    const float* pch = phi + (size_t)(b * KK + kl) * NN + e * 512 + ch * 256;
#pragma unroll
    for (int j = 0; j < 8; ++j) {
      const int nn = (j * 8 + nq) * 4;
      const float4 pv = *reinterpret_cast<const float4*>(pch + nn);
      smem[(nn + 0) * 33 + kl] = pv.x;
      smem[(nn + 1) * 33 + kl] = pv.y;
      smem[(nn + 2) * 33 + kl] = pv.z;
      smem[(nn + 3) * 33 + kl] = pv.w;
    }
    __syncthreads();
#pragma unroll
    for (int i = 0; i < 8; ++i) {
      const int nl = g * 32 + i * 4;
      const float p0 = smem[(nl + 0) * 33 + k];
      const float p1 = smem[(nl + 1) * 33 + k];
      const float p2 = smem[(nl + 2) * 33 + k];
      const float p3 = smem[(nl + 3) * 33 + k];
#pragma unroll
      for (int c = 0; c < 8; ++c) {
        const float4 xv =
            *reinterpret_cast<const float4*>(xb + (size_t)c * NN + ch * 256 + nl);
        acc[c] = fmaf(xv.x, p0, acc[c]);
        acc[c] = fmaf(xv.y, p1, acc[c]);
        acc[c] = fmaf(xv.z, p2, acc[c]);
        acc[c] = fmaf(xv.w, p3, acc[c]);
      }
    }
    __syncthreads();
  }
#pragma unroll
  for (int c = 0; c < 8; ++c) smem[(g * 8 + c) * 33 + k] = acc[c];
  __syncthreads();
  {
    const int c2 = tid & 7, k2 = tid >> 3;
    float s = 0.f;
#pragma unroll
    for (int gg = 0; gg < 8; ++gg) s += smem[(gg * 8 + c2) * 33 + k2];
    m1e[((size_t)(e * BB + b) * KK + k2) * CC + ct * 8 + c2] = s;
  }
  // ---- arrival signal + possible k_code epilogue ----
  __shared__ int srank;
  __syncthreads();  // drains vmcnt: all block stores complete before signal
  if (tid == 0)
    srank = __hip_atomic_fetch_add(cnt, 1, __ATOMIC_ACQ_REL,
                                   __HIP_MEMORY_SCOPE_AGENT);
  __syncthreads();
  if (srank < XPT_BLOCKS - EPI) return;
  const int uid = srank - (XPT_BLOCKS - EPI);
  const int bb = uid >> 5;
  const int kk = uid & 31;
  if (tid == 0) {
    while (__hip_atomic_load(cnt, __ATOMIC_ACQUIRE,
                             __HIP_MEMORY_SCOPE_AGENT) < XPT_BLOCKS)
      __builtin_amdgcn_s_sleep(4);
  }
  __syncthreads();
  (void)__hip_atomic_load(cnt, __ATOMIC_ACQUIRE, __HIP_MEMORY_SCOPE_AGENT);
  // k_code body (d = tid), identical math to round 5
  {
    const int d = tid;
    float* m1s = smem;
    __shared__ float rbx[4];
    const float invS =
        1.f / (Sp[(size_t)bb * KK + kk] + Sp[((size_t)BB + bb) * KK + kk]);
    float m = 0.f;
#pragma unroll
    for (int e2 = 0; e2 < NE; ++e2)
      m += m1e[(((size_t)e2 * BB + bb) * KK + kk) * CC + d];
    m1s[d] = m * invS;
    __syncthreads();
    float cd = 0.f;
    const float* wt = wth + (size_t)d * CC;
#pragma unroll 4
    for (int c = 0; c < CC; c += 4) {
      const float4 w4 = *reinterpret_cast<const float4*>(wt + c);
      cd = fmaf(w4.x, m1s[c + 0], cd);
      cd = fmaf(w4.y, m1s[c + 1], cd);
      cd = fmaf(w4.z, m1s[c + 2], cd);
      cd = fmaf(w4.w, m1s[c + 3], cd);
    }
    float ss = wredsum(cd * cd);
    if ((d & 63) == 0) rbx[d >> 6] = ss;
    __syncthreads();
    const float nrm = sqrtf(rbx[0] + rbx[1] + rbx[2] + rbx[3]);
    const float inv = 1.f / fmaxf(nrm, 1e-12f);
    cd *= inv;
    const float sc = scale[(size_t)d * KK + kk];
    const float s2 = sc * sc;
    code[((size_t)bb * DD + d) * KK + kk] = cd;
    bc2[((size_t)bb * DD + d) * KK + kk] = 2.f * s2 * cd;
    if (bb == 0) s2g[(size_t)d * KK + kk] = s2;
    float tt = wredsum(s2 * cd * cd);
    __syncthreads();
    if ((d & 63) == 0) rbx[d >> 6] = tt;
    __syncthreads();
    if (d == 0) t3[bb * KK + kk] = rbx[0] + rbx[1] + rbx[2] + rbx[3];
  }
}

// Kernel 3: dist + softmax(k) -> Q (d_out) + qpart.  (round-5 proven design)
// grid = B*64, block 512 (8 waves = 8 d-stripes of 32).
__global__ __launch_bounds__(512) void k_dist(const float* __restrict__ x,
                                              const float* __restrict__ s2g,
                                              const float* __restrict__ bc2,
                                              const float* __restrict__ t3,
                                              float* __restrict__ qout,
                                              float* __restrict__ qpart) {
  const int b = blockIdx.x >> 6;
  const int tile = blockIdx.x & 63;
  const int n0 = tile * 64;
  const int tid = threadIdx.x;
  const int lane = tid & 63;
  const int wid = __builtin_amdgcn_readfirstlane(tid >> 6);  // 0..7
  const int d0 = wid * 32;
  __shared__ float lds[4 * 64 * 33];
  __shared__ float smax[64 * 9];
  __shared__ float ssum[64 * 9];
  float accA[32], accB[32];
#pragma unroll
  for (int k = 0; k < 32; ++k) { accA[k] = 0.f; accB[k] = 0.f; }
  const float* xb = x + ((size_t)b * CC + d0) * NN + n0 + lane;
  const float* s2b = s2g + (size_t)d0 * KK;
  const float* bcb = bc2 + ((size_t)b * DD + d0) * KK;
#pragma unroll 2
  for (int dd = 0; dd < 32; ++dd) {
    const float xv = xb[(size_t)dd * NN];
    const float x2 = xv * xv;
    const float* s2r = s2b + dd * KK;
    const float* bcr = bcb + dd * KK;
#pragma unroll
    for (int k = 0; k < 32; ++k) {
      accA[k] = fmaf(x2, s2r[k], accA[k]);
      accB[k] = fmaf(xv, bcr[k], accB[k]);
    }
  }
  if (wid >= 4) {
    float* Lp = lds + ((size_t)((wid - 4) * 64 + lane)) * 33;
#pragma unroll
    for (int k = 0; k < 32; ++k) Lp[k] = accA[k] - accB[k];
  }
  __syncthreads();
  if (wid < 4) {
    float* Lp = lds + ((size_t)(wid * 64 + lane)) * 33;
#pragma unroll
    for (int k = 0; k < 32; ++k) Lp[k] += accA[k] - accB[k];
  }
  __syncthreads();
  const int n = lane;
  const int kq = wid;
  float vals[4];
#pragma unroll
  for (int j = 0; j < 4; ++j) {
    const int k = kq * 4 + j;
    float s = 0.f;
#pragma unroll
    for (int g = 0; g < 4; ++g) s += lds[((size_t)(g * 64 + n)) * 33 + k];
    vals[j] = -0.5f * (s + t3[b * KK + k]);
  }
  float m4 = fmaxf(fmaxf(vals[0], vals[1]), fmaxf(vals[2], vals[3]));
  smax[n * 9 + kq] = m4;
  __syncthreads();
  float m = smax[n * 9 + 0];
#pragma unroll
  for (int g = 1; g < 8; ++g) m = fmaxf(m, smax[n * 9 + g]);
  float e[4];
  float ps = 0.f;
#pragma unroll
  for (int j = 0; j < 4; ++j) {
    e[j] = __expf(vals[j] - m);
    ps += e[j];
  }
  ssum[n * 9 + kq] = ps;
  __syncthreads();
  float tot = 0.f;
#pragma unroll
  for (int g = 0; g < 8; ++g) tot += ssum[n * 9 + g];
  const float inv = 1.f / tot;
  float4 q4;
  q4.x = e[0] * inv; q4.y = e[1] * inv;
  q4.z = e[2] * inv; q4.w = e[3] * inv;
  *reinterpret_cast<float4*>(qout + ((size_t)b * NN + n0 + n) * KK + kq * 4) =
      q4;
  float qs[4] = {q4.x, q4.y, q4.z, q4.w};
#pragma unroll
  for (int j = 0; j < 4; ++j) {
    const float v = wredsum(qs[j]);
    if (n == 0) qpart[((size_t)b * KK + kq * 4 + j) * NT2 + tile] = v;
  }
}

// Kernel 4: Znum partials (round-5 k_xq body) + fused k_z epilogue.
// grid = 1024, block 256. znq8 layout [e][b][k][c].
__global__ __launch_bounds__(256) void k_xq_z(
    const float* __restrict__ x, const float* __restrict__ q,
    float* __restrict__ znq8, const float* __restrict__ code,
    const float* __restrict__ scale, const float* __restrict__ qpart,
    float* __restrict__ zout, int* __restrict__ cnt) {
  const int e = blockIdx.x & 7;
  const int ct = (blockIdx.x >> 3) & 31;
  const int b = blockIdx.x >> 8;
  const int tid = threadIdx.x;
  const int k = tid & 31;
  const int g = tid >> 5;  // 8 n-groups of 64
  const int n0 = e * 512 + g * 64;
  const float* xb = x + (size_t)(b * CC + ct * 8) * NN;
  const float* qb = q + (size_t)b * NN * KK + k;
  float acc[8] = {0.f, 0.f, 0.f, 0.f, 0.f, 0.f, 0.f, 0.f};
  for (int n = n0; n < n0 + 64; n += 4) {
    const float p0 = qb[(size_t)(n + 0) * KK];
    const float p1 = qb[(size_t)(n + 1) * KK];
    const float p2 = qb[(size_t)(n + 2) * KK];
    const float p3 = qb[(size_t)(n + 3) * KK];
#pragma unroll
    for (int c = 0; c < 8; ++c) {
      const float4 xv = *reinterpret_cast<const float4*>(xb + (size_t)c * NN + n);
      acc[c] = fmaf(xv.x, p0, acc[c]);
      acc[c] = fmaf(xv.y, p1, acc[c]);
      acc[c] = fmaf(xv.z, p2, acc[c]);
      acc[c] = fmaf(xv.w, p3, acc[c]);
    }
  }
  __shared__ float lds[8 * 8 * 33];
#pragma unroll
  for (int c = 0; c < 8; ++c) lds[(g * 8 + c) * 33 + k] = acc[c];
  __syncthreads();
  {
    const int c2 = tid & 7, k2 = tid >> 3;
    float s = 0.f;
#pragma unroll
    for (int gg = 0; gg < 8; ++gg) s += lds[(gg * 8 + c2) * 33 + k2];
    znq8[((size_t)(e * BB + b) * KK + k2) * CC + ct * 8 + c2] = s;
  }
  // ---- arrival signal + possible k_z epilogue ----
  __shared__ int srank;
  __syncthreads();
  if (tid == 0)
    srank = __hip_atomic_fetch_add(cnt, 1, __ATOMIC_ACQ_REL,
                                   __HIP_MEMORY_SCOPE_AGENT);
  __syncthreads();
  if (srank < XPT_BLOCKS - EPI) return;
  const int uid = srank - (XPT_BLOCKS - EPI);
  const int bb = uid >> 5;
  const int kk = uid & 31;
  if (tid == 0) {
    while (__hip_atomic_load(cnt, __ATOMIC_ACQUIRE,
                             __HIP_MEMORY_SCOPE_AGENT) < XPT_BLOCKS)
      __builtin_amdgcn_s_sleep(4);
  }
  __syncthreads();
  (void)__hip_atomic_load(cnt, __ATOMIC_ACQUIRE, __HIP_MEMORY_SCOPE_AGENT);
  // k_z body (d = tid), identical math to round 5
  {
    const int d = tid;
    __shared__ float rbx[4];
    float qp = (d < NT2) ? qpart[((size_t)bb * KK + kk) * NT2 + d] : 0.f;
    qp = wredsum(qp);
    if ((d & 63) == 0) rbx[d >> 6] = qp;
    __syncthreads();
    const float qs2 = rbx[0] + rbx[1] + rbx[2] + rbx[3];
    float zn = 0.f;
#pragma unroll
    for (int e2 = 0; e2 < NE; ++e2)
      zn += znq8[(((size_t)e2 * BB + bb) * KK + kk) * CC + d];
    const float cdv = code[((size_t)bb * DD + d) * KK + kk];
    const float z_ = scale[(size_t)d * KK + kk] * (zn / qs2 - cdv);
    float ss = wredsum(z_ * z_);
    __syncthreads();
    if ((d & 63) == 0) rbx[d >> 6] = ss;
    __syncthreads();
    const float rn = 1.f / sqrtf(rbx[0] + rbx[1] + rbx[2] + rbx[3]);
    zout[((size_t)bb * DD + d) * KK + kk] = z_ * rn;
  }
}

extern "C" void kernel_launch(void* const* d_in, const int* in_sizes, int n_in,
                              void* d_out, int out_size, void* d_ws,
                              size_t ws_size, hipStream_t stream) {
  const float* x = (const float*)d_in[0];
  const float* wth = (const float*)d_in[1];
  const float* wphi = (const float*)d_in[2];
  const float* scale = (const float*)d_in[3];
  float* out = (float*)d_out;
  float* zout = out;                         // B*D*K = 32768
  float* qout = out + (size_t)BB * DD * KK;  // B*N*K = 524288
  float* ws = (float*)d_ws;
  float* phi = ws;                                 // B*K*N   = 524288
  float* Sp = phi + (size_t)BB * NN * KK;          // 2*B*K   = 256
  float* m1e = Sp + 2 * (size_t)BB * KK;           // 8*B*K*C = 262144
  float* code = m1e + (size_t)NE * BB * KK * CC;   // B*D*K   = 32768
  float* bc2 = code + (size_t)BB * DD * KK;        // B*D*K   = 32768
  float* s2g = bc2 + (size_t)BB * DD * KK;         // D*K     = 8192
  float* t3 = s2g + (size_t)DD * KK;               // B*K     = 128
  float* qpart = t3 + BB * KK;                     // B*K*64  = 8192
  float* znq8 = qpart + (size_t)BB * KK * NT2;     // 8*B*K*C = 262144
  int* cnts = (int*)(znq8 + (size_t)NE * BB * KK * CC);  // 2 ints

  k_phi<<<BB * KK * 2, 256, 0, stream>>>(x, wphi, phi, Sp, cnts);
  k_xpT_code<<<XPT_BLOCKS, 256, 0, stream>>>(x, phi, m1e, Sp, wth, scale, code,
                                             bc2, s2g, t3, cnts);
  k_dist<<<BB * NT2, 512, 0, stream>>>(x, s2g, bc2, t3, qout, qpart);
  k_xq_z<<<XPT_BLOCKS, 256, 0, stream>>>(x, qout, znq8, code, scale, qpart,
                                         zout, cnts + 1);
}

// Round 10
// 82.486 us; speedup vs baseline: 1.7716x; 1.7716x over previous
//
#include <hip/hip_runtime.h>
#include <math.h>

#define BB 4
#define CC 256
#define NN 4096
#define KK 32
#define DD 256
#define GG 8    // C/K
#define NT2 64  // n-tiles of 64 in k_dist
#define NE 8    // n-eighths in the two GEMM kernels

__device__ __forceinline__ float wredsum(float v) {
#pragma unroll
  for (int o = 32; o > 0; o >>= 1) v += __shfl_xor(v, o, 64);
  return v;
}

// Kernel 1: phi = exp(grouped conv) unnormalized + Sp half-partials.
// phi layout [b][k][n]. grid = B*K*2, block 256.
__global__ __launch_bounds__(256) void k_phi(const float* __restrict__ x,
                                             const float* __restrict__ wphi,
                                             float* __restrict__ phi,
                                             float* __restrict__ Sp) {
  const int half = blockIdx.x & 1;
  const int k = (blockIdx.x >> 1) & 31;
  const int b = blockIdx.x >> 6;
  const int tid = threadIdx.x;
  const float* xb = x + (size_t)(b * CC + k * GG) * NN + half * 2048;
  float w[GG];
#pragma unroll
  for (int j = 0; j < GG; ++j) w[j] = wphi[k * GG + j];
  float4 v[2];
  float sum = 0.f;
#pragma unroll
  for (int i = 0; i < 2; ++i) {
    const int n = i * 1024 + tid * 4;
    float4 s = make_float4(0.f, 0.f, 0.f, 0.f);
#pragma unroll
    for (int j = 0; j < GG; ++j) {
      const float4 xv = *reinterpret_cast<const float4*>(xb + (size_t)j * NN + n);
      s.x = fmaf(xv.x, w[j], s.x);
      s.y = fmaf(xv.y, w[j], s.y);
      s.z = fmaf(xv.z, w[j], s.z);
      s.w = fmaf(xv.w, w[j], s.w);
    }
    v[i].x = __expf(s.x);
    v[i].y = __expf(s.y);
    v[i].z = __expf(s.z);
    v[i].w = __expf(s.w);
    sum += v[i].x + v[i].y + v[i].z + v[i].w;
  }
  float* pk = phi + (size_t)(b * KK + k) * NN + half * 2048;
#pragma unroll
  for (int i = 0; i < 2; ++i) {
    *reinterpret_cast<float4*>(pk + i * 1024 + tid * 4) = v[i];
  }
  __shared__ float rb[4];
  sum = wredsum(sum);
  if ((tid & 63) == 0) rb[tid >> 6] = sum;
  __syncthreads();
  if (tid == 0)
    Sp[((size_t)half * BB + b) * KK + k] = rb[0] + rb[1] + rb[2] + rb[3];
}

// Kernel 2: M1 partials over n-eighths. phi [b][k][n] staged via LDS transpose.
// grid = B*32ct*NE = 1024, block 256. m1e layout [e][b][k][c].
__global__ __launch_bounds__(256) void k_xpT(const float* __restrict__ x,
                                             const float* __restrict__ phi,
                                             float* __restrict__ m1e) {
  const int e = blockIdx.x & 7;
  const int ct = (blockIdx.x >> 3) & 31;
  const int b = blockIdx.x >> 8;
  const int tid = threadIdx.x;
  __shared__ float smem[256 * 33];
  const int kl = tid >> 3;  // stage: phi row (k)
  const int nq = tid & 7;
  const int k = tid & 31;   // compute: k lane
  const int g = tid >> 5;   // compute: n-group
  const float* xb = x + (size_t)(b * CC + ct * 8) * NN + e * 512;
  float acc[8] = {0.f, 0.f, 0.f, 0.f, 0.f, 0.f, 0.f, 0.f};
#pragma unroll
  for (int ch = 0; ch < 2; ++ch) {
    const float* pch = phi + (size_t)(b * KK + kl) * NN + e * 512 + ch * 256;
#pragma unroll
    for (int j = 0; j < 8; ++j) {
      const int nn = (j * 8 + nq) * 4;
      const float4 pv = *reinterpret_cast<const float4*>(pch + nn);
      smem[(nn + 0) * 33 + kl] = pv.x;
      smem[(nn + 1) * 33 + kl] = pv.y;
      smem[(nn + 2) * 33 + kl] = pv.z;
      smem[(nn + 3) * 33 + kl] = pv.w;
    }
    __syncthreads();
#pragma unroll
    for (int i = 0; i < 8; ++i) {
      const int nl = g * 32 + i * 4;
      const float p0 = smem[(nl + 0) * 33 + k];
      const float p1 = smem[(nl + 1) * 33 + k];
      const float p2 = smem[(nl + 2) * 33 + k];
      const float p3 = smem[(nl + 3) * 33 + k];
#pragma unroll
      for (int c = 0; c < 8; ++c) {
        const float4 xv =
            *reinterpret_cast<const float4*>(xb + (size_t)c * NN + ch * 256 + nl);
        acc[c] = fmaf(xv.x, p0, acc[c]);
        acc[c] = fmaf(xv.y, p1, acc[c]);
        acc[c] = fmaf(xv.z, p2, acc[c]);
        acc[c] = fmaf(xv.w, p3, acc[c]);
      }
    }
    __syncthreads();
  }
#pragma unroll
  for (int c = 0; c < 8; ++c) smem[(g * 8 + c) * 33 + k] = acc[c];
  __syncthreads();
  const int c2 = tid & 7, k2 = tid >> 3;
  float s = 0.f;
#pragma unroll
  for (int gg = 0; gg < 8; ++gg) s += smem[(gg * 8 + c2) * 33 + k2];
  m1e[((size_t)(e * BB + b) * KK + k2) * CC + ct * 8 + c2] = s;
}

// Kernel 3: M1 = (sum_e m1e)/S; code = w_theta @ M1 normalized over d;
// emit code, bc2 = 2*s2*code, s2, t3. grid = B*K, block 256.
// 4-way ILP on the dot (serial-chain fix: ~1 wave/SIMD here, no TLP hiding).
__global__ __launch_bounds__(256) void k_code(const float* __restrict__ m1e,
                                              const float* __restrict__ Sp,
                                              const float* __restrict__ wth,
                                              const float* __restrict__ scale,
                                              float* __restrict__ code,
                                              float* __restrict__ bc2,
                                              float* __restrict__ s2g,
                                              float* __restrict__ t3) {
  const int b = blockIdx.x >> 5;
  const int k = blockIdx.x & 31;
  const int d = threadIdx.x;
  const float invS =
      1.f / (Sp[(size_t)b * KK + k] + Sp[((size_t)BB + b) * KK + k]);
  __shared__ __align__(16) float m1s[CC];
  float m = 0.f;
#pragma unroll
  for (int e = 0; e < NE; ++e)
    m += m1e[((size_t)(e * BB + b) * KK + k) * CC + d];
  m1s[d] = m * invS;
  __syncthreads();
  float c0 = 0.f, c1 = 0.f, c2 = 0.f, c3 = 0.f;
  const float* wt = wth + (size_t)d * CC;
#pragma unroll 4
  for (int c = 0; c < CC; c += 4) {
    const float4 w4 = *reinterpret_cast<const float4*>(wt + c);
    const float4 m4 = *reinterpret_cast<const float4*>(&m1s[c]);
    c0 = fmaf(w4.x, m4.x, c0);
    c1 = fmaf(w4.y, m4.y, c1);
    c2 = fmaf(w4.z, m4.z, c2);
    c3 = fmaf(w4.w, m4.w, c3);
  }
  float cd = (c0 + c1) + (c2 + c3);
  __shared__ float rb[4];
  float ss = wredsum(cd * cd);
  if ((d & 63) == 0) rb[d >> 6] = ss;
  __syncthreads();
  const float nrm = sqrtf(rb[0] + rb[1] + rb[2] + rb[3]);
  const float inv = 1.f / fmaxf(nrm, 1e-12f);
  cd *= inv;
  const float sc = scale[(size_t)d * KK + k];
  const float s2 = sc * sc;
  code[((size_t)b * DD + d) * KK + k] = cd;
  bc2[((size_t)b * DD + d) * KK + k] = 2.f * s2 * cd;
  if (b == 0) s2g[(size_t)d * KK + k] = s2;
  float tt = wredsum(s2 * cd * cd);
  __syncthreads();
  if ((d & 63) == 0) rb[d >> 6] = tt;
  __syncthreads();
  if (d == 0) t3[b * KK + k] = rb[0] + rb[1] + rb[2] + rb[3];
}

// Kernel 4: dist + softmax(k) -> Q (d_out) + qpart.
// grid = B*64 (64-n tiles), block 512 (8 waves = 8 d-stripes of 32).
// Wave-uniform s2/bc2 rows -> SGPR scalar broadcasts; lanes = 64 n.
__global__ __launch_bounds__(512) void k_dist(const float* __restrict__ x,
                                              const float* __restrict__ s2g,
                                              const float* __restrict__ bc2,
                                              const float* __restrict__ t3,
                                              float* __restrict__ qout,
                                              float* __restrict__ qpart) {
  const int b = blockIdx.x >> 6;
  const int tile = blockIdx.x & 63;
  const int n0 = tile * 64;
  const int tid = threadIdx.x;
  const int lane = tid & 63;
  const int wid = __builtin_amdgcn_readfirstlane(tid >> 6);  // 0..7
  const int d0 = wid * 32;
  __shared__ float lds[4 * 64 * 33];
  __shared__ float smax[64 * 9];
  __shared__ float ssum[64 * 9];
  float accA[32], accB[32];
#pragma unroll
  for (int k = 0; k < 32; ++k) { accA[k] = 0.f; accB[k] = 0.f; }
  const float* xb = x + ((size_t)b * CC + d0) * NN + n0 + lane;
  const float* s2b = s2g + (size_t)d0 * KK;
  const float* bcb = bc2 + ((size_t)b * DD + d0) * KK;
#pragma unroll 2
  for (int dd = 0; dd < 32; ++dd) {
    const float xv = xb[(size_t)dd * NN];
    const float x2 = xv * xv;
    const float* s2r = s2b + dd * KK;
    const float* bcr = bcb + dd * KK;
#pragma unroll
    for (int k = 0; k < 32; ++k) {
      accA[k] = fmaf(x2, s2r[k], accA[k]);
      accB[k] = fmaf(xv, bcr[k], accB[k]);
    }
  }
  if (wid >= 4) {
    float* Lp = lds + ((size_t)((wid - 4) * 64 + lane)) * 33;
#pragma unroll
    for (int k = 0; k < 32; ++k) Lp[k] = accA[k] - accB[k];
  }
  __syncthreads();
  if (wid < 4) {
    float* Lp = lds + ((size_t)(wid * 64 + lane)) * 33;
#pragma unroll
    for (int k = 0; k < 32; ++k) Lp[k] += accA[k] - accB[k];
  }
  __syncthreads();
  const int n = lane;
  const int kq = wid;
  float vals[4];
#pragma unroll
  for (int j = 0; j < 4; ++j) {
    const int k = kq * 4 + j;
    float s = 0.f;
#pragma unroll
    for (int g = 0; g < 4; ++g) s += lds[((size_t)(g * 64 + n)) * 33 + k];
    vals[j] = -0.5f * (s + t3[b * KK + k]);
  }
  float m4 = fmaxf(fmaxf(vals[0], vals[1]), fmaxf(vals[2], vals[3]));
  smax[n * 9 + kq] = m4;
  __syncthreads();
  float m = smax[n * 9 + 0];
#pragma unroll
  for (int g = 1; g < 8; ++g) m = fmaxf(m, smax[n * 9 + g]);
  float e[4];
  float ps = 0.f;
#pragma unroll
  for (int j = 0; j < 4; ++j) {
    e[j] = __expf(vals[j] - m);
    ps += e[j];
  }
  ssum[n * 9 + kq] = ps;
  __syncthreads();
  float tot = 0.f;
#pragma unroll
  for (int g = 0; g < 8; ++g) tot += ssum[n * 9 + g];
  const float inv = 1.f / tot;
  float4 q4;
  q4.x = e[0] * inv; q4.y = e[1] * inv;
  q4.z = e[2] * inv; q4.w = e[3] * inv;
  *reinterpret_cast<float4*>(qout + ((size_t)b * NN + n0 + n) * KK + kq * 4) =
      q4;
  float qs[4] = {q4.x, q4.y, q4.z, q4.w};
#pragma unroll
  for (int j = 0; j < 4; ++j) {
    const float v = wredsum(qs[j]);
    if (n == 0) qpart[((size_t)b * KK + kq * 4 + j) * NT2 + tile] = v;
  }
}

// Kernel 5: znq8[e][b][k][c] = sum_{n in eighth} x[c,n] * Q[n,k].
// Q LDS-staged in 256-n chunks (coalesced float4 in, padded broadcast out) —
// removes the 64-distinct-line scalar gather of the round-5 version.
// grid = B*32ct*NE = 1024, block 256.
__global__ __launch_bounds__(256) void k_xq(const float* __restrict__ x,
                                            const float* __restrict__ q,
                                            float* __restrict__ znq8) {
  const int e = blockIdx.x & 7;
  const int ct = (blockIdx.x >> 3) & 31;
  const int b = blockIdx.x >> 8;
  const int tid = threadIdx.x;
  __shared__ float qs[256 * 33];  // Q[n_local][k], pad 33
  const int k = tid & 31;
  const int g = tid >> 5;  // 8 groups of 32 n
  float acc[8] = {0.f, 0.f, 0.f, 0.f, 0.f, 0.f, 0.f, 0.f};
  const float* xb = x + (size_t)(b * CC + ct * 8) * NN;
#pragma unroll
  for (int ch = 0; ch < 2; ++ch) {
    const int n0 = e * 512 + ch * 256;
    // stage: thread tid loads Q row n0+tid (32 floats = 8 float4, coalesced
    // across lanes at each j step)
    const float* qr = q + ((size_t)b * NN + n0 + tid) * KK;
#pragma unroll
    for (int j = 0; j < 8; ++j) {
      const float4 qv = *reinterpret_cast<const float4*>(qr + j * 4);
      float* dst = qs + tid * 33 + j * 4;
      dst[0] = qv.x; dst[1] = qv.y; dst[2] = qv.z; dst[3] = qv.w;
    }
    __syncthreads();
#pragma unroll
    for (int i = 0; i < 8; ++i) {
      const int nl = g * 32 + i * 4;
      const float p0 = qs[(nl + 0) * 33 + k];
      const float p1 = qs[(nl + 1) * 33 + k];
      const float p2 = qs[(nl + 2) * 33 + k];
      const float p3 = qs[(nl + 3) * 33 + k];
#pragma unroll
      for (int c = 0; c < 8; ++c) {
        const float4 xv =
            *reinterpret_cast<const float4*>(xb + (size_t)c * NN + n0 + nl);
        acc[c] = fmaf(xv.x, p0, acc[c]);
        acc[c] = fmaf(xv.y, p1, acc[c]);
        acc[c] = fmaf(xv.z, p2, acc[c]);
        acc[c] = fmaf(xv.w, p3, acc[c]);
      }
    }
    __syncthreads();
  }
  // cross-g reduce (reuse qs)
#pragma unroll
  for (int c = 0; c < 8; ++c) qs[(g * 8 + c) * 33 + k] = acc[c];
  __syncthreads();
  const int c2 = tid & 7, k2 = tid >> 3;
  float s = 0.f;
#pragma unroll
  for (int gg = 0; gg < 8; ++gg) s += qs[(gg * 8 + c2) * 33 + k2];
  znq8[((size_t)(e * BB + b) * KK + k2) * CC + ct * 8 + c2] = s;
}

// Kernel 6: Qsum reduce + Z = scale*(Znum/Qsum - code), d-normalized.
// grid = B*K, block 256.
__global__ __launch_bounds__(256) void k_z(const float* __restrict__ znq8,
                                           const float* __restrict__ code,
                                           const float* __restrict__ scale,
                                           const float* __restrict__ qpart,
                                           float* __restrict__ zout) {
  const int b = blockIdx.x >> 5;
  const int k = blockIdx.x & 31;
  const int d = threadIdx.x;
  __shared__ float rb[4];
  float qp = (d < NT2) ? qpart[((size_t)b * KK + k) * NT2 + d] : 0.f;
  qp = wredsum(qp);
  if ((d & 63) == 0) rb[d >> 6] = qp;
  __syncthreads();
  const float qs = rb[0] + rb[1] + rb[2] + rb[3];
  float zn = 0.f;
#pragma unroll
  for (int e = 0; e < NE; ++e)
    zn += znq8[((size_t)(e * BB + b) * KK + k) * CC + d];
  const float cd = code[((size_t)b * DD + d) * KK + k];
  const float z_ = scale[(size_t)d * KK + k] * (zn / qs - cd);
  float ss = wredsum(z_ * z_);
  __syncthreads();
  if ((d & 63) == 0) rb[d >> 6] = ss;
  __syncthreads();
  const float rn = 1.f / sqrtf(rb[0] + rb[1] + rb[2] + rb[3]);
  zout[((size_t)b * DD + d) * KK + k] = z_ * rn;
}

extern "C" void kernel_launch(void* const* d_in, const int* in_sizes, int n_in,
                              void* d_out, int out_size, void* d_ws,
                              size_t ws_size, hipStream_t stream) {
  const float* x = (const float*)d_in[0];
  const float* wth = (const float*)d_in[1];
  const float* wphi = (const float*)d_in[2];
  const float* scale = (const float*)d_in[3];
  float* out = (float*)d_out;
  float* zout = out;                         // B*D*K = 32768
  float* qout = out + (size_t)BB * DD * KK;  // B*N*K = 524288
  float* ws = (float*)d_ws;
  float* phi = ws;                                 // B*K*N   = 524288
  float* Sp = phi + (size_t)BB * NN * KK;          // 2*B*K   = 256
  float* m1e = Sp + 2 * (size_t)BB * KK;           // 8*B*K*C = 262144
  float* code = m1e + (size_t)NE * BB * KK * CC;   // B*D*K   = 32768
  float* bc2 = code + (size_t)BB * DD * KK;        // B*D*K   = 32768
  float* s2g = bc2 + (size_t)BB * DD * KK;         // D*K     = 8192
  float* t3 = s2g + (size_t)DD * KK;               // B*K     = 128
  float* qpart = t3 + BB * KK;                     // B*K*64  = 8192
  float* znq8 = qpart + (size_t)BB * KK * NT2;     // 8*B*K*C = 262144

  k_phi<<<BB * KK * 2, 256, 0, stream>>>(x, wphi, phi, Sp);
  k_xpT<<<BB * 32 * NE, 256, 0, stream>>>(x, phi, m1e);
  k_code<<<BB * KK, 256, 0, stream>>>(m1e, Sp, wth, scale, code, bc2, s2g, t3);
  k_dist<<<BB * NT2, 512, 0, stream>>>(x, s2g, bc2, t3, qout, qpart);
  k_xq<<<BB * 32 * NE, 256, 0, stream>>>(x, qout, znq8);
  k_z<<<BB * KK, 256, 0, stream>>>(znq8, code, scale, qpart, zout);
}

// Round 11
// 78.179 us; speedup vs baseline: 1.8692x; 1.0551x over previous
//
#include <hip/hip_runtime.h>
#include <math.h>

#define BB 4
#define CC 256
#define NN 4096
#define KK 32
#define DD 256
#define GG 8    // C/K
#define NT2 64  // n-tiles of 64 in k_dist
#define NE 8    // n-eighths in the two GEMM kernels
#define NSL 64  // n-slices of 64 in k_phi

__device__ __forceinline__ float wredsum(float v) {
#pragma unroll
  for (int o = 32; o > 0; o >>= 1) v += __shfl_xor(v, o, 64);
  return v;
}

// Kernel 1: phi = exp(grouped conv), UNNORMALIZED, written as [b][n][k]
// (the proven-fast GEMM input layout) + per-slice exp-sum partials SpE.
// grid = B*64 (64-n slices), block 256.
__global__ __launch_bounds__(256) void k_phi(const float* __restrict__ x,
                                             const float* __restrict__ wphi,
                                             float* __restrict__ phi,
                                             float* __restrict__ SpE) {
  const int b = blockIdx.x >> 6;
  const int sl = blockIdx.x & 63;
  const int n0 = sl * 64;
  const int tid = threadIdx.x;
  __shared__ float phis[64 * 33];  // [n_local][k], stride 33
  __shared__ float sred[8 * 33];
  // conv + exp: thread (kk = tid>>3, m = tid&7) -> 8 n for one k
  {
    const int kk = tid >> 3;
    const int m = tid & 7;
    const float* xb = x + (size_t)(b * CC + kk * GG) * NN + n0 + m * 8;
    float w[GG];
#pragma unroll
    for (int j = 0; j < GG; ++j) w[j] = wphi[kk * GG + j];
    float4 s0 = make_float4(0.f, 0.f, 0.f, 0.f);
    float4 s1 = make_float4(0.f, 0.f, 0.f, 0.f);
#pragma unroll
    for (int j = 0; j < GG; ++j) {
      const float4 xa = *reinterpret_cast<const float4*>(xb + (size_t)j * NN);
      const float4 xc = *reinterpret_cast<const float4*>(xb + (size_t)j * NN + 4);
      s0.x = fmaf(xa.x, w[j], s0.x);
      s0.y = fmaf(xa.y, w[j], s0.y);
      s0.z = fmaf(xa.z, w[j], s0.z);
      s0.w = fmaf(xa.w, w[j], s0.w);
      s1.x = fmaf(xc.x, w[j], s1.x);
      s1.y = fmaf(xc.y, w[j], s1.y);
      s1.z = fmaf(xc.z, w[j], s1.z);
      s1.w = fmaf(xc.w, w[j], s1.w);
    }
    const int nb = m * 8;
    phis[(nb + 0) * 33 + kk] = __expf(s0.x);
    phis[(nb + 1) * 33 + kk] = __expf(s0.y);
    phis[(nb + 2) * 33 + kk] = __expf(s0.z);
    phis[(nb + 3) * 33 + kk] = __expf(s0.w);
    phis[(nb + 4) * 33 + kk] = __expf(s1.x);
    phis[(nb + 5) * 33 + kk] = __expf(s1.y);
    phis[(nb + 6) * 33 + kk] = __expf(s1.z);
    phis[(nb + 7) * 33 + kk] = __expf(s1.w);
  }
  __syncthreads();
  // SpE partials: thread (k = tid&31, g = tid>>5) sums 8 n
  {
    const int k = tid & 31;
    const int g = tid >> 5;
    float s = 0.f;
#pragma unroll
    for (int i = 0; i < 8; ++i) s += phis[(g * 8 + i) * 33 + k];
    sred[g * 33 + k] = s;
  }
  // write phi[b][n0+n][k]: thread t -> 8 consecutive flat floats
  __syncthreads();
  {
    const int n = tid >> 2;
    const int k0 = (tid & 3) * 8;
    float v[8];
#pragma unroll
    for (int j = 0; j < 8; ++j) v[j] = phis[n * 33 + k0 + j];
    float* dst = phi + ((size_t)b * NN + n0 + n) * KK + k0;
    float4 o0 = make_float4(v[0], v[1], v[2], v[3]);
    float4 o1 = make_float4(v[4], v[5], v[6], v[7]);
    *reinterpret_cast<float4*>(dst + 0) = o0;
    *reinterpret_cast<float4*>(dst + 4) = o1;
    if (tid < 32) {
      float s = 0.f;
#pragma unroll
      for (int g = 0; g < 8; ++g) s += sred[g * 33 + tid];
      SpE[((size_t)sl * BB + b) * KK + tid] = s;
    }
  }
}

// Kernel 2 (used twice): out[e][b][k][c] = sum_{n in eighth} x[c,n]*P[b,n,k].
// P in [b][n][k]: scalar loads coalesced over the 32 k lanes (proven pattern).
// grid = B*32ct*NE = 1024, block 256.
__global__ __launch_bounds__(256) void k_xp(const float* __restrict__ x,
                                            const float* __restrict__ p,
                                            float* __restrict__ outq) {
  const int e = blockIdx.x & 7;
  const int ct = (blockIdx.x >> 3) & 31;
  const int b = blockIdx.x >> 8;
  const int tid = threadIdx.x;
  const int k = tid & 31;
  const int g = tid >> 5;  // 8 n-groups of 64
  const int n0 = e * 512 + g * 64;
  const float* xb = x + (size_t)(b * CC + ct * 8) * NN;
  const float* pb = p + (size_t)b * NN * KK + k;
  float acc[8] = {0.f, 0.f, 0.f, 0.f, 0.f, 0.f, 0.f, 0.f};
  for (int n = n0; n < n0 + 64; n += 4) {
    const float p0 = pb[(size_t)(n + 0) * KK];
    const float p1 = pb[(size_t)(n + 1) * KK];
    const float p2 = pb[(size_t)(n + 2) * KK];
    const float p3 = pb[(size_t)(n + 3) * KK];
#pragma unroll
    for (int c = 0; c < 8; ++c) {
      const float4 xv = *reinterpret_cast<const float4*>(xb + (size_t)c * NN + n);
      acc[c] = fmaf(xv.x, p0, acc[c]);
      acc[c] = fmaf(xv.y, p1, acc[c]);
      acc[c] = fmaf(xv.z, p2, acc[c]);
      acc[c] = fmaf(xv.w, p3, acc[c]);
    }
  }
  __shared__ float lds[8 * 8 * 33];
#pragma unroll
  for (int c = 0; c < 8; ++c) lds[(g * 8 + c) * 33 + k] = acc[c];
  __syncthreads();
  const int c2 = tid & 7, k2 = tid >> 3;
  float s = 0.f;
#pragma unroll
  for (int gg = 0; gg < 8; ++gg) s += lds[(gg * 8 + c2) * 33 + k2];
  outq[((size_t)(e * BB + b) * KK + k2) * CC + ct * 8 + c2] = s;
}

// Kernel 3: S = sum_64 SpE; M1 = (sum_e m1e)/S; code = w_theta @ M1
// normalized over d; emit code, bc2 = 2*s2*code, s2, t3. grid = B*K, block 256.
__global__ __launch_bounds__(256) void k_code(const float* __restrict__ m1e,
                                              const float* __restrict__ SpE,
                                              const float* __restrict__ wth,
                                              const float* __restrict__ scale,
                                              float* __restrict__ code,
                                              float* __restrict__ bc2,
                                              float* __restrict__ s2g,
                                              float* __restrict__ t3) {
  const int b = blockIdx.x >> 5;
  const int k = blockIdx.x & 31;
  const int d = threadIdx.x;
  __shared__ __align__(16) float m1s[CC];
  __shared__ float rb[4];
  float sp = (d < NSL) ? SpE[((size_t)d * BB + b) * KK + k] : 0.f;
  sp = wredsum(sp);
  if ((d & 63) == 0) rb[d >> 6] = sp;
  __syncthreads();
  const float invS = 1.f / (rb[0] + rb[1] + rb[2] + rb[3]);
  float m = 0.f;
#pragma unroll
  for (int e = 0; e < NE; ++e)
    m += m1e[((size_t)(e * BB + b) * KK + k) * CC + d];
  m1s[d] = m * invS;
  __syncthreads();
  float c0 = 0.f, c1 = 0.f, c2 = 0.f, c3 = 0.f;
  const float* wt = wth + (size_t)d * CC;
#pragma unroll 4
  for (int c = 0; c < CC; c += 4) {
    const float4 w4 = *reinterpret_cast<const float4*>(wt + c);
    const float4 m4 = *reinterpret_cast<const float4*>(&m1s[c]);
    c0 = fmaf(w4.x, m4.x, c0);
    c1 = fmaf(w4.y, m4.y, c1);
    c2 = fmaf(w4.z, m4.z, c2);
    c3 = fmaf(w4.w, m4.w, c3);
  }
  float cd = (c0 + c1) + (c2 + c3);
  float ss = wredsum(cd * cd);
  __syncthreads();
  if ((d & 63) == 0) rb[d >> 6] = ss;
  __syncthreads();
  const float nrm = sqrtf(rb[0] + rb[1] + rb[2] + rb[3]);
  const float inv = 1.f / fmaxf(nrm, 1e-12f);
  cd *= inv;
  const float sc = scale[(size_t)d * KK + k];
  const float s2 = sc * sc;
  code[((size_t)b * DD + d) * KK + k] = cd;
  bc2[((size_t)b * DD + d) * KK + k] = 2.f * s2 * cd;
  if (b == 0) s2g[(size_t)d * KK + k] = s2;
  float tt = wredsum(s2 * cd * cd);
  __syncthreads();
  if ((d & 63) == 0) rb[d >> 6] = tt;
  __syncthreads();
  if (d == 0) t3[b * KK + k] = rb[0] + rb[1] + rb[2] + rb[3];
}

// Kernel 4: dist + softmax(k) -> Q (d_out) + qpart.  (round-5 proven design)
// grid = B*64, block 512 (8 waves = 8 d-stripes of 32).
__global__ __launch_bounds__(512) void k_dist(const float* __restrict__ x,
                                              const float* __restrict__ s2g,
                                              const float* __restrict__ bc2,
                                              const float* __restrict__ t3,
                                              float* __restrict__ qout,
                                              float* __restrict__ qpart) {
  const int b = blockIdx.x >> 6;
  const int tile = blockIdx.x & 63;
  const int n0 = tile * 64;
  const int tid = threadIdx.x;
  const int lane = tid & 63;
  const int wid = __builtin_amdgcn_readfirstlane(tid >> 6);  // 0..7
  const int d0 = wid * 32;
  __shared__ float lds[4 * 64 * 33];
  __shared__ float smax[64 * 9];
  __shared__ float ssum[64 * 9];
  float accA[32], accB[32];
#pragma unroll
  for (int k = 0; k < 32; ++k) { accA[k] = 0.f; accB[k] = 0.f; }
  const float* xb = x + ((size_t)b * CC + d0) * NN + n0 + lane;
  const float* s2b = s2g + (size_t)d0 * KK;
  const float* bcb = bc2 + ((size_t)b * DD + d0) * KK;
#pragma unroll 2
  for (int dd = 0; dd < 32; ++dd) {
    const float xv = xb[(size_t)dd * NN];
    const float x2 = xv * xv;
    const float* s2r = s2b + dd * KK;
    const float* bcr = bcb + dd * KK;
#pragma unroll
    for (int k = 0; k < 32; ++k) {
      accA[k] = fmaf(x2, s2r[k], accA[k]);
      accB[k] = fmaf(xv, bcr[k], accB[k]);
    }
  }
  if (wid >= 4) {
    float* Lp = lds + ((size_t)((wid - 4) * 64 + lane)) * 33;
#pragma unroll
    for (int k = 0; k < 32; ++k) Lp[k] = accA[k] - accB[k];
  }
  __syncthreads();
  if (wid < 4) {
    float* Lp = lds + ((size_t)(wid * 64 + lane)) * 33;
#pragma unroll
    for (int k = 0; k < 32; ++k) Lp[k] += accA[k] - accB[k];
  }
  __syncthreads();
  const int n = lane;
  const int kq = wid;
  float vals[4];
#pragma unroll
  for (int j = 0; j < 4; ++j) {
    const int k = kq * 4 + j;
    float s = 0.f;
#pragma unroll
    for (int g = 0; g < 4; ++g) s += lds[((size_t)(g * 64 + n)) * 33 + k];
    vals[j] = -0.5f * (s + t3[b * KK + k]);
  }
  float m4 = fmaxf(fmaxf(vals[0], vals[1]), fmaxf(vals[2], vals[3]));
  smax[n * 9 + kq] = m4;
  __syncthreads();
  float m = smax[n * 9 + 0];
#pragma unroll
  for (int g = 1; g < 8; ++g) m = fmaxf(m, smax[n * 9 + g]);
  float e[4];
  float ps = 0.f;
#pragma unroll
  for (int j = 0; j < 4; ++j) {
    e[j] = __expf(vals[j] - m);
    ps += e[j];
  }
  ssum[n * 9 + kq] = ps;
  __syncthreads();
  float tot = 0.f;
#pragma unroll
  for (int g = 0; g < 8; ++g) tot += ssum[n * 9 + g];
  const float inv = 1.f / tot;
  float4 q4;
  q4.x = e[0] * inv; q4.y = e[1] * inv;
  q4.z = e[2] * inv; q4.w = e[3] * inv;
  *reinterpret_cast<float4*>(qout + ((size_t)b * NN + n0 + n) * KK + kq * 4) =
      q4;
  float qs[4] = {q4.x, q4.y, q4.z, q4.w};
#pragma unroll
  for (int j = 0; j < 4; ++j) {
    const float v = wredsum(qs[j]);
    if (n == 0) qpart[((size_t)b * KK + kq * 4 + j) * NT2 + tile] = v;
  }
}

// Kernel 5: Qsum reduce + Z = scale*(Znum/Qsum - code), d-normalized.
// grid = B*K, block 256.
__global__ __launch_bounds__(256) void k_z(const float* __restrict__ znq8,
                                           const float* __restrict__ code,
                                           const float* __restrict__ scale,
                                           const float* __restrict__ qpart,
                                           float* __restrict__ zout) {
  const int b = blockIdx.x >> 5;
  const int k = blockIdx.x & 31;
  const int d = threadIdx.x;
  __shared__ float rb[4];
  float qp = (d < NT2) ? qpart[((size_t)b * KK + k) * NT2 + d] : 0.f;
  qp = wredsum(qp);
  if ((d & 63) == 0) rb[d >> 6] = qp;
  __syncthreads();
  const float qs = rb[0] + rb[1] + rb[2] + rb[3];
  float zn = 0.f;
#pragma unroll
  for (int e = 0; e < NE; ++e)
    zn += znq8[((size_t)(e * BB + b) * KK + k) * CC + d];
  const float cd = code[((size_t)b * DD + d) * KK + k];
  const float z_ = scale[(size_t)d * KK + k] * (zn / qs - cd);
  float ss = wredsum(z_ * z_);
  __syncthreads();
  if ((d & 63) == 0) rb[d >> 6] = ss;
  __syncthreads();
  const float rn = 1.f / sqrtf(rb[0] + rb[1] + rb[2] + rb[3]);
  zout[((size_t)b * DD + d) * KK + k] = z_ * rn;
}

extern "C" void kernel_launch(void* const* d_in, const int* in_sizes, int n_in,
                              void* d_out, int out_size, void* d_ws,
                              size_t ws_size, hipStream_t stream) {
  const float* x = (const float*)d_in[0];
  const float* wth = (const float*)d_in[1];
  const float* wphi = (const float*)d_in[2];
  const float* scale = (const float*)d_in[3];
  float* out = (float*)d_out;
  float* zout = out;                         // B*D*K = 32768
  float* qout = out + (size_t)BB * DD * KK;  // B*N*K = 524288
  float* ws = (float*)d_ws;
  float* phi = ws;                                 // B*N*K    = 524288
  float* SpE = phi + (size_t)BB * NN * KK;         // 64*B*K   = 8192
  float* m1e = SpE + (size_t)NSL * BB * KK;        // 8*B*K*C  = 262144
  float* code = m1e + (size_t)NE * BB * KK * CC;   // B*D*K    = 32768
  float* bc2 = code + (size_t)BB * DD * KK;        // B*D*K    = 32768
  float* s2g = bc2 + (size_t)BB * DD * KK;         // D*K      = 8192
  float* t3 = s2g + (size_t)DD * KK;               // B*K      = 128
  float* qpart = t3 + BB * KK;                     // B*K*64   = 8192
  float* znq8 = qpart + (size_t)BB * KK * NT2;     // 8*B*K*C  = 262144

  k_phi<<<BB * NSL, 256, 0, stream>>>(x, wphi, phi, SpE);
  k_xp<<<BB * 32 * NE, 256, 0, stream>>>(x, phi, m1e);
  k_code<<<BB * KK, 256, 0, stream>>>(m1e, SpE, wth, scale, code, bc2, s2g, t3);
  k_dist<<<BB * NT2, 512, 0, stream>>>(x, s2g, bc2, t3, qout, qpart);
  k_xp<<<BB * 32 * NE, 256, 0, stream>>>(x, qout, znq8);
  k_z<<<BB * KK, 256, 0, stream>>>(znq8, code, scale, qpart, zout);
}

// Round 12
// 76.668 us; speedup vs baseline: 1.9061x; 1.0197x over previous
//
#include <hip/hip_runtime.h>
#include <math.h>

#define BB 4
#define CC 256
#define NN 4096
#define KK 32
#define DD 256
#define GG 8    // C/K
#define NT2 64  // n-tiles of 64 in k_dist
#define NE 8    // n-eighths in k_xp (Q path)
#define NSL 64  // n-slices of 64 in k_pm1

__device__ __forceinline__ float wredsum(float v) {
#pragma unroll
  for (int o = 32; o > 0; o >>= 1) v += __shfl_xor(v, o, 64);
  return v;
}

// Kernel 1: fused phi (grouped conv + exp, LDS-only) + m1 partials.
// grid = B * 64 n-slices * 4 c-quarters = 1024 blocks, block 256
// (same block count / per-thread FMA as the proven k_xp shape).
// m1e layout [e][b][k][c]; SpE[e][b][k] written by ct==0 blocks.
__global__ __launch_bounds__(256) void k_pm1(const float* __restrict__ x,
                                             const float* __restrict__ wphi,
                                             float* __restrict__ m1e,
                                             float* __restrict__ SpE) {
  const int b = blockIdx.x >> 8;
  const int ct = (blockIdx.x >> 6) & 3;  // 64-c quarter
  const int e = blockIdx.x & 63;         // 64-n slice
  const int n0 = e * 64;
  const int tid = threadIdx.x;
  __shared__ float phis[64 * 33];  // [n_local][k], stride 33 (conflict-free)
  // --- conv + exp into LDS: thread (kk = tid>>3, m = tid&7) -> 8 n of one k --
  {
    const int kk = tid >> 3;
    const int m = tid & 7;
    const float* xb = x + (size_t)(b * CC + kk * GG) * NN + n0 + m * 8;
    float w[GG];
#pragma unroll
    for (int j = 0; j < GG; ++j) w[j] = wphi[kk * GG + j];
    float4 s0 = make_float4(0.f, 0.f, 0.f, 0.f);
    float4 s1 = make_float4(0.f, 0.f, 0.f, 0.f);
#pragma unroll
    for (int j = 0; j < GG; ++j) {
      const float4 xa = *reinterpret_cast<const float4*>(xb + (size_t)j * NN);
      const float4 xc = *reinterpret_cast<const float4*>(xb + (size_t)j * NN + 4);
      s0.x = fmaf(xa.x, w[j], s0.x);
      s0.y = fmaf(xa.y, w[j], s0.y);
      s0.z = fmaf(xa.z, w[j], s0.z);
      s0.w = fmaf(xa.w, w[j], s0.w);
      s1.x = fmaf(xc.x, w[j], s1.x);
      s1.y = fmaf(xc.y, w[j], s1.y);
      s1.z = fmaf(xc.z, w[j], s1.z);
      s1.w = fmaf(xc.w, w[j], s1.w);
    }
    const int nb = m * 8;
    phis[(nb + 0) * 33 + kk] = __expf(s0.x);
    phis[(nb + 1) * 33 + kk] = __expf(s0.y);
    phis[(nb + 2) * 33 + kk] = __expf(s0.z);
    phis[(nb + 3) * 33 + kk] = __expf(s0.w);
    phis[(nb + 4) * 33 + kk] = __expf(s1.x);
    phis[(nb + 5) * 33 + kk] = __expf(s1.y);
    phis[(nb + 6) * 33 + kk] = __expf(s1.z);
    phis[(nb + 7) * 33 + kk] = __expf(s1.w);
  }
  __syncthreads();
  // --- SpE partials (only ct==0 blocks; unique writer per (e,b,k)) ---
  if (ct == 0 && tid < 32) {
    float s = 0.f;
#pragma unroll 8
    for (int n = 0; n < 64; ++n) s += phis[n * 33 + tid];
    SpE[((size_t)e * BB + b) * KK + tid] = s;
  }
  // --- m1: thread (k = tid&31, g = tid>>5) sums ALL 64 n for 8 channels ---
  const int k = tid & 31;
  const int g = tid >> 5;
  const int c0 = ct * 64 + g * 8;
  const float* xm = x + (size_t)(b * CC + c0) * NN + n0;
  float acc[8] = {0.f, 0.f, 0.f, 0.f, 0.f, 0.f, 0.f, 0.f};
  for (int n = 0; n < 64; n += 4) {
    const float p0 = phis[(n + 0) * 33 + k];
    const float p1 = phis[(n + 1) * 33 + k];
    const float p2 = phis[(n + 2) * 33 + k];
    const float p3 = phis[(n + 3) * 33 + k];
#pragma unroll
    for (int c = 0; c < 8; ++c) {
      const float4 xv = *reinterpret_cast<const float4*>(xm + (size_t)c * NN + n);
      acc[c] = fmaf(xv.x, p0, acc[c]);
      acc[c] = fmaf(xv.y, p1, acc[c]);
      acc[c] = fmaf(xv.z, p2, acc[c]);
      acc[c] = fmaf(xv.w, p3, acc[c]);
    }
  }
  // fully reduced over this slice's n -> direct write (8 floats/thread, 1 MB total)
  float* mb = m1e + (((size_t)e * BB + b) * KK + k) * CC + c0;
  float4 o0 = make_float4(acc[0], acc[1], acc[2], acc[3]);
  float4 o1 = make_float4(acc[4], acc[5], acc[6], acc[7]);
  *reinterpret_cast<float4*>(mb + 0) = o0;
  *reinterpret_cast<float4*>(mb + 4) = o1;
}

// Kernel 2: S = sum_64 SpE; M1 = (sum_e m1e)/S; code = w_theta @ M1
// normalized over d; emit code, bc2 = 2*s2*code, s2, t3. grid = B*K, block 256.
__global__ __launch_bounds__(256) void k_code(const float* __restrict__ m1e,
                                              const float* __restrict__ SpE,
                                              const float* __restrict__ wth,
                                              const float* __restrict__ scale,
                                              float* __restrict__ code,
                                              float* __restrict__ bc2,
                                              float* __restrict__ s2g,
                                              float* __restrict__ t3) {
  const int b = blockIdx.x >> 5;
  const int k = blockIdx.x & 31;
  const int d = threadIdx.x;
  __shared__ __align__(16) float m1s[CC];
  __shared__ float rb[4];
  float sp = (d < NSL) ? SpE[((size_t)d * BB + b) * KK + k] : 0.f;
  sp = wredsum(sp);
  if ((d & 63) == 0) rb[d >> 6] = sp;
  __syncthreads();
  const float invS = 1.f / (rb[0] + rb[1] + rb[2] + rb[3]);
  float m = 0.f;
  for (int e = 0; e < NSL; ++e)
    m += m1e[(((size_t)e * BB + b) * KK + k) * CC + d];
  m1s[d] = m * invS;
  __syncthreads();
  float c0 = 0.f, c1 = 0.f, c2 = 0.f, c3 = 0.f;
  const float* wt = wth + (size_t)d * CC;
#pragma unroll 4
  for (int c = 0; c < CC; c += 4) {
    const float4 w4 = *reinterpret_cast<const float4*>(wt + c);
    const float4 m4 = *reinterpret_cast<const float4*>(&m1s[c]);
    c0 = fmaf(w4.x, m4.x, c0);
    c1 = fmaf(w4.y, m4.y, c1);
    c2 = fmaf(w4.z, m4.z, c2);
    c3 = fmaf(w4.w, m4.w, c3);
  }
  float cd = (c0 + c1) + (c2 + c3);
  float ss = wredsum(cd * cd);
  __syncthreads();
  if ((d & 63) == 0) rb[d >> 6] = ss;
  __syncthreads();
  const float nrm = sqrtf(rb[0] + rb[1] + rb[2] + rb[3]);
  const float inv = 1.f / fmaxf(nrm, 1e-12f);
  cd *= inv;
  const float sc = scale[(size_t)d * KK + k];
  const float s2 = sc * sc;
  code[((size_t)b * DD + d) * KK + k] = cd;
  bc2[((size_t)b * DD + d) * KK + k] = 2.f * s2 * cd;
  if (b == 0) s2g[(size_t)d * KK + k] = s2;
  float tt = wredsum(s2 * cd * cd);
  __syncthreads();
  if ((d & 63) == 0) rb[d >> 6] = tt;
  __syncthreads();
  if (d == 0) t3[b * KK + k] = rb[0] + rb[1] + rb[2] + rb[3];
}

// Kernel 3: dist + softmax(k) -> Q (d_out) + qpart.  (proven design)
// grid = B*64, block 512 (8 waves = 8 d-stripes of 32).
__global__ __launch_bounds__(512) void k_dist(const float* __restrict__ x,
                                              const float* __restrict__ s2g,
                                              const float* __restrict__ bc2,
                                              const float* __restrict__ t3,
                                              float* __restrict__ qout,
                                              float* __restrict__ qpart) {
  const int b = blockIdx.x >> 6;
  const int tile = blockIdx.x & 63;
  const int n0 = tile * 64;
  const int tid = threadIdx.x;
  const int lane = tid & 63;
  const int wid = __builtin_amdgcn_readfirstlane(tid >> 6);  // 0..7
  const int d0 = wid * 32;
  __shared__ float lds[4 * 64 * 33];
  __shared__ float smax[64 * 9];
  __shared__ float ssum[64 * 9];
  float accA[32], accB[32];
#pragma unroll
  for (int k = 0; k < 32; ++k) { accA[k] = 0.f; accB[k] = 0.f; }
  const float* xb = x + ((size_t)b * CC + d0) * NN + n0 + lane;
  const float* s2b = s2g + (size_t)d0 * KK;
  const float* bcb = bc2 + ((size_t)b * DD + d0) * KK;
#pragma unroll 2
  for (int dd = 0; dd < 32; ++dd) {
    const float xv = xb[(size_t)dd * NN];
    const float x2 = xv * xv;
    const float* s2r = s2b + dd * KK;
    const float* bcr = bcb + dd * KK;
#pragma unroll
    for (int k = 0; k < 32; ++k) {
      accA[k] = fmaf(x2, s2r[k], accA[k]);
      accB[k] = fmaf(xv, bcr[k], accB[k]);
    }
  }
  if (wid >= 4) {
    float* Lp = lds + ((size_t)((wid - 4) * 64 + lane)) * 33;
#pragma unroll
    for (int k = 0; k < 32; ++k) Lp[k] = accA[k] - accB[k];
  }
  __syncthreads();
  if (wid < 4) {
    float* Lp = lds + ((size_t)(wid * 64 + lane)) * 33;
#pragma unroll
    for (int k = 0; k < 32; ++k) Lp[k] += accA[k] - accB[k];
  }
  __syncthreads();
  const int n = lane;
  const int kq = wid;
  float vals[4];
#pragma unroll
  for (int j = 0; j < 4; ++j) {
    const int k = kq * 4 + j;
    float s = 0.f;
#pragma unroll
    for (int g = 0; g < 4; ++g) s += lds[((size_t)(g * 64 + n)) * 33 + k];
    vals[j] = -0.5f * (s + t3[b * KK + k]);
  }
  float m4 = fmaxf(fmaxf(vals[0], vals[1]), fmaxf(vals[2], vals[3]));
  smax[n * 9 + kq] = m4;
  __syncthreads();
  float m = smax[n * 9 + 0];
#pragma unroll
  for (int g = 1; g < 8; ++g) m = fmaxf(m, smax[n * 9 + g]);
  float e[4];
  float ps = 0.f;
#pragma unroll
  for (int j = 0; j < 4; ++j) {
    e[j] = __expf(vals[j] - m);
    ps += e[j];
  }
  ssum[n * 9 + kq] = ps;
  __syncthreads();
  float tot = 0.f;
#pragma unroll
  for (int g = 0; g < 8; ++g) tot += ssum[n * 9 + g];
  const float inv = 1.f / tot;
  float4 q4;
  q4.x = e[0] * inv; q4.y = e[1] * inv;
  q4.z = e[2] * inv; q4.w = e[3] * inv;
  *reinterpret_cast<float4*>(qout + ((size_t)b * NN + n0 + n) * KK + kq * 4) =
      q4;
  float qs[4] = {q4.x, q4.y, q4.z, q4.w};
#pragma unroll
  for (int j = 0; j < 4; ++j) {
    const float v = wredsum(qs[j]);
    if (n == 0) qpart[((size_t)b * KK + kq * 4 + j) * NT2 + tile] = v;
  }
}

// Kernel 4: znq8[e][b][k][c] = sum_{n in eighth} x[c,n] * Q[b,n,k].
// Q in [b][n][k]: scalar loads coalesced over the 32 k lanes (proven pattern).
// grid = B*32ct*NE = 1024, block 256.
__global__ __launch_bounds__(256) void k_xp(const float* __restrict__ x,
                                            const float* __restrict__ p,
                                            float* __restrict__ outq) {
  const int e = blockIdx.x & 7;
  const int ct = (blockIdx.x >> 3) & 31;
  const int b = blockIdx.x >> 8;
  const int tid = threadIdx.x;
  const int k = tid & 31;
  const int g = tid >> 5;  // 8 n-groups of 64
  const int n0 = e * 512 + g * 64;
  const float* xb = x + (size_t)(b * CC + ct * 8) * NN;
  const float* pb = p + (size_t)b * NN * KK + k;
  float acc[8] = {0.f, 0.f, 0.f, 0.f, 0.f, 0.f, 0.f, 0.f};
  for (int n = n0; n < n0 + 64; n += 4) {
    const float p0 = pb[(size_t)(n + 0) * KK];
    const float p1 = pb[(size_t)(n + 1) * KK];
    const float p2 = pb[(size_t)(n + 2) * KK];
    const float p3 = pb[(size_t)(n + 3) * KK];
#pragma unroll
    for (int c = 0; c < 8; ++c) {
      const float4 xv = *reinterpret_cast<const float4*>(xb + (size_t)c * NN + n);
      acc[c] = fmaf(xv.x, p0, acc[c]);
      acc[c] = fmaf(xv.y, p1, acc[c]);
      acc[c] = fmaf(xv.z, p2, acc[c]);
      acc[c] = fmaf(xv.w, p3, acc[c]);
    }
  }
  __shared__ float lds[8 * 8 * 33];
#pragma unroll
  for (int c = 0; c < 8; ++c) lds[(g * 8 + c) * 33 + k] = acc[c];
  __syncthreads();
  const int c2 = tid & 7, k2 = tid >> 3;
  float s = 0.f;
#pragma unroll
  for (int gg = 0; gg < 8; ++gg) s += lds[(gg * 8 + c2) * 33 + k2];
  outq[((size_t)(e * BB + b) * KK + k2) * CC + ct * 8 + c2] = s;
}

// Kernel 5: Qsum reduce + Z = scale*(Znum/Qsum - code), d-normalized.
// grid = B*K, block 256.
__global__ __launch_bounds__(256) void k_z(const float* __restrict__ znq8,
                                           const float* __restrict__ code,
                                           const float* __restrict__ scale,
                                           const float* __restrict__ qpart,
                                           float* __restrict__ zout) {
  const int b = blockIdx.x >> 5;
  const int k = blockIdx.x & 31;
  const int d = threadIdx.x;
  __shared__ float rb[4];
  float qp = (d < NT2) ? qpart[((size_t)b * KK + k) * NT2 + d] : 0.f;
  qp = wredsum(qp);
  if ((d & 63) == 0) rb[d >> 6] = qp;
  __syncthreads();
  const float qs = rb[0] + rb[1] + rb[2] + rb[3];
  float zn = 0.f;
#pragma unroll
  for (int e = 0; e < NE; ++e)
    zn += znq8[((size_t)(e * BB + b) * KK + k) * CC + d];
  const float cd = code[((size_t)b * DD + d) * KK + k];
  const float z_ = scale[(size_t)d * KK + k] * (zn / qs - cd);
  float ss = wredsum(z_ * z_);
  __syncthreads();
  if ((d & 63) == 0) rb[d >> 6] = ss;
  __syncthreads();
  const float rn = 1.f / sqrtf(rb[0] + rb[1] + rb[2] + rb[3]);
  zout[((size_t)b * DD + d) * KK + k] = z_ * rn;
}

extern "C" void kernel_launch(void* const* d_in, const int* in_sizes, int n_in,
                              void* d_out, int out_size, void* d_ws,
                              size_t ws_size, hipStream_t stream) {
  const float* x = (const float*)d_in[0];
  const float* wth = (const float*)d_in[1];
  const float* wphi = (const float*)d_in[2];
  const float* scale = (const float*)d_in[3];
  float* out = (float*)d_out;
  float* zout = out;                         // B*D*K = 32768
  float* qout = out + (size_t)BB * DD * KK;  // B*N*K = 524288
  float* ws = (float*)d_ws;
  float* SpE = ws;                                  // 64*B*K   = 8192
  float* m1e = SpE + (size_t)NSL * BB * KK;         // 64*B*K*C = 2097152
  float* code = m1e + (size_t)NSL * BB * KK * CC;   // B*D*K    = 32768
  float* bc2 = code + (size_t)BB * DD * KK;         // B*D*K    = 32768
  float* s2g = bc2 + (size_t)BB * DD * KK;          // D*K      = 8192
  float* t3 = s2g + (size_t)DD * KK;                // B*K      = 128
  float* qpart = t3 + BB * KK;                      // B*K*64   = 8192
  float* znq8 = qpart + (size_t)BB * KK * NT2;      // 8*B*K*C  = 262144

  k_pm1<<<BB * NSL * 4, 256, 0, stream>>>(x, wphi, m1e, SpE);
  k_code<<<BB * KK, 256, 0, stream>>>(m1e, SpE, wth, scale, code, bc2, s2g, t3);
  k_dist<<<BB * NT2, 512, 0, stream>>>(x, s2g, bc2, t3, qout, qpart);
  k_xp<<<BB * 32 * NE, 256, 0, stream>>>(x, qout, znq8);
  k_z<<<BB * KK, 256, 0, stream>>>(znq8, code, scale, qpart, zout);
}

// Round 13
// 72.679 us; speedup vs baseline: 2.0107x; 1.0549x over previous
//
#include <hip/hip_runtime.h>
#include <math.h>

#define BB 4
#define CC 256
#define NN 4096
#define KK 32
#define DD 256
#define GG 8    // C/K
#define NT2 64  // n-tiles of 64 in k_dist
#define NE 8    // n-eighths in k_xp (Q path)
#define NSL 64  // n-slices of 64 in k_pm1

__device__ __forceinline__ float wredsum(float v) {
#pragma unroll
  for (int o = 32; o > 0; o >>= 1) v += __shfl_xor(v, o, 64);
  return v;
}

// Kernel 1: fused phi (grouped conv + exp, LDS-only) + m1 partials.
// grid = B * 64 n-slices * 4 c-quarters = 1024 blocks, block 256.
// m1e layout [e][b][k][c]; SpE[e][b][k] written by ct==0 blocks.
__global__ __launch_bounds__(256) void k_pm1(const float* __restrict__ x,
                                             const float* __restrict__ wphi,
                                             float* __restrict__ m1e,
                                             float* __restrict__ SpE) {
  const int b = blockIdx.x >> 8;
  const int ct = (blockIdx.x >> 6) & 3;  // 64-c quarter
  const int e = blockIdx.x & 63;         // 64-n slice
  const int n0 = e * 64;
  const int tid = threadIdx.x;
  __shared__ float phis[64 * 33];  // [n_local][k], stride 33 (conflict-free)
  {
    const int kk = tid >> 3;
    const int m = tid & 7;
    const float* xb = x + (size_t)(b * CC + kk * GG) * NN + n0 + m * 8;
    float w[GG];
#pragma unroll
    for (int j = 0; j < GG; ++j) w[j] = wphi[kk * GG + j];
    float4 s0 = make_float4(0.f, 0.f, 0.f, 0.f);
    float4 s1 = make_float4(0.f, 0.f, 0.f, 0.f);
#pragma unroll
    for (int j = 0; j < GG; ++j) {
      const float4 xa = *reinterpret_cast<const float4*>(xb + (size_t)j * NN);
      const float4 xc = *reinterpret_cast<const float4*>(xb + (size_t)j * NN + 4);
      s0.x = fmaf(xa.x, w[j], s0.x);
      s0.y = fmaf(xa.y, w[j], s0.y);
      s0.z = fmaf(xa.z, w[j], s0.z);
      s0.w = fmaf(xa.w, w[j], s0.w);
      s1.x = fmaf(xc.x, w[j], s1.x);
      s1.y = fmaf(xc.y, w[j], s1.y);
      s1.z = fmaf(xc.z, w[j], s1.z);
      s1.w = fmaf(xc.w, w[j], s1.w);
    }
    const int nb = m * 8;
    phis[(nb + 0) * 33 + kk] = __expf(s0.x);
    phis[(nb + 1) * 33 + kk] = __expf(s0.y);
    phis[(nb + 2) * 33 + kk] = __expf(s0.z);
    phis[(nb + 3) * 33 + kk] = __expf(s0.w);
    phis[(nb + 4) * 33 + kk] = __expf(s1.x);
    phis[(nb + 5) * 33 + kk] = __expf(s1.y);
    phis[(nb + 6) * 33 + kk] = __expf(s1.z);
    phis[(nb + 7) * 33 + kk] = __expf(s1.w);
  }
  __syncthreads();
  if (ct == 0 && tid < 32) {
    float s = 0.f;
#pragma unroll 8
    for (int n = 0; n < 64; ++n) s += phis[n * 33 + tid];
    SpE[((size_t)e * BB + b) * KK + tid] = s;
  }
  const int k = tid & 31;
  const int g = tid >> 5;
  const int c0 = ct * 64 + g * 8;
  const float* xm = x + (size_t)(b * CC + c0) * NN + n0;
  float acc[8] = {0.f, 0.f, 0.f, 0.f, 0.f, 0.f, 0.f, 0.f};
  for (int n = 0; n < 64; n += 4) {
    const float p0 = phis[(n + 0) * 33 + k];
    const float p1 = phis[(n + 1) * 33 + k];
    const float p2 = phis[(n + 2) * 33 + k];
    const float p3 = phis[(n + 3) * 33 + k];
#pragma unroll
    for (int c = 0; c < 8; ++c) {
      const float4 xv = *reinterpret_cast<const float4*>(xm + (size_t)c * NN + n);
      acc[c] = fmaf(xv.x, p0, acc[c]);
      acc[c] = fmaf(xv.y, p1, acc[c]);
      acc[c] = fmaf(xv.z, p2, acc[c]);
      acc[c] = fmaf(xv.w, p3, acc[c]);
    }
  }
  float* mb = m1e + (((size_t)e * BB + b) * KK + k) * CC + c0;
  float4 o0 = make_float4(acc[0], acc[1], acc[2], acc[3]);
  float4 o1 = make_float4(acc[4], acc[5], acc[6], acc[7]);
  *reinterpret_cast<float4*>(mb + 0) = o0;
  *reinterpret_cast<float4*>(mb + 4) = o1;
}

// Kernel 2: S = sum_64 SpE; M1 = (sum_e m1e)/S; code = w_theta @ M1
// normalized over d; emit code, bc2, s2, t3. grid = B*K, block 256.
__global__ __launch_bounds__(256) void k_code(const float* __restrict__ m1e,
                                              const float* __restrict__ SpE,
                                              const float* __restrict__ wth,
                                              const float* __restrict__ scale,
                                              float* __restrict__ code,
                                              float* __restrict__ bc2,
                                              float* __restrict__ s2g,
                                              float* __restrict__ t3) {
  const int b = blockIdx.x >> 5;
  const int k = blockIdx.x & 31;
  const int d = threadIdx.x;
  __shared__ __align__(16) float m1s[CC];
  __shared__ float rb[4];
  float sp = (d < NSL) ? SpE[((size_t)d * BB + b) * KK + k] : 0.f;
  sp = wredsum(sp);
  if ((d & 63) == 0) rb[d >> 6] = sp;
  __syncthreads();
  const float invS = 1.f / (rb[0] + rb[1] + rb[2] + rb[3]);
  float m = 0.f;
  for (int e = 0; e < NSL; ++e)
    m += m1e[(((size_t)e * BB + b) * KK + k) * CC + d];
  m1s[d] = m * invS;
  __syncthreads();
  float c0 = 0.f, c1 = 0.f, c2 = 0.f, c3 = 0.f;
  const float* wt = wth + (size_t)d * CC;
#pragma unroll 4
  for (int c = 0; c < CC; c += 4) {
    const float4 w4 = *reinterpret_cast<const float4*>(wt + c);
    const float4 m4 = *reinterpret_cast<const float4*>(&m1s[c]);
    c0 = fmaf(w4.x, m4.x, c0);
    c1 = fmaf(w4.y, m4.y, c1);
    c2 = fmaf(w4.z, m4.z, c2);
    c3 = fmaf(w4.w, m4.w, c3);
  }
  float cd = (c0 + c1) + (c2 + c3);
  float ss = wredsum(cd * cd);
  __syncthreads();
  if ((d & 63) == 0) rb[d >> 6] = ss;
  __syncthreads();
  const float nrm = sqrtf(rb[0] + rb[1] + rb[2] + rb[3]);
  const float inv = 1.f / fmaxf(nrm, 1e-12f);
  cd *= inv;
  const float sc = scale[(size_t)d * KK + k];
  const float s2 = sc * sc;
  code[((size_t)b * DD + d) * KK + k] = cd;
  bc2[((size_t)b * DD + d) * KK + k] = 2.f * s2 * cd;
  if (b == 0) s2g[(size_t)d * KK + k] = s2;
  float tt = wredsum(s2 * cd * cd);
  __syncthreads();
  if ((d & 63) == 0) rb[d >> 6] = tt;
  __syncthreads();
  if (d == 0) t3[b * KK + k] = rb[0] + rb[1] + rb[2] + rb[3];
}

// Kernel 3: dist + softmax(k) -> Q (d_out) + qpart.
// grid = B*64 (64-n tiles), block 1024 (16 waves = 16 d-stripes of 16).
// 2 blocks/CU (thread cap) = 4 waves/SIMD; s2/bc2 rows stay wave-uniform.
__global__ __launch_bounds__(1024) void k_dist(const float* __restrict__ x,
                                               const float* __restrict__ s2g,
                                               const float* __restrict__ bc2,
                                               const float* __restrict__ t3,
                                               float* __restrict__ qout,
                                               float* __restrict__ qpart) {
  const int b = blockIdx.x >> 6;
  const int tile = blockIdx.x & 63;
  const int n0 = tile * 64;
  const int tid = threadIdx.x;
  const int lane = tid & 63;
  const int wid = __builtin_amdgcn_readfirstlane(tid >> 6);  // 0..15
  const int d0 = wid * 16;
  __shared__ float lds[4 * 64 * 33];
  __shared__ float smax[64 * 9];
  __shared__ float ssum[64 * 9];
  float accA[32], accB[32];
#pragma unroll
  for (int k = 0; k < 32; ++k) { accA[k] = 0.f; accB[k] = 0.f; }
  const float* xb = x + ((size_t)b * CC + d0) * NN + n0 + lane;
  const float* s2b = s2g + (size_t)d0 * KK;
  const float* bcb = bc2 + ((size_t)b * DD + d0) * KK;
#pragma unroll 2
  for (int dd = 0; dd < 16; ++dd) {
    const float xv = xb[(size_t)dd * NN];
    const float x2 = xv * xv;
    const float* s2r = s2b + dd * KK;
    const float* bcr = bcb + dd * KK;
#pragma unroll
    for (int k = 0; k < 32; ++k) {
      accA[k] = fmaf(x2, s2r[k], accA[k]);
      accB[k] = fmaf(xv, bcr[k], accB[k]);
    }
  }
  // 16-wave cross-reduce into 4 padded buffers: 4-phase barrier cascade
  if (wid >= 12) {
    float* Lp = lds + ((size_t)((wid - 12) * 64 + lane)) * 33;
#pragma unroll
    for (int k = 0; k < 32; ++k) Lp[k] = accA[k] - accB[k];
  }
  __syncthreads();
  if (wid >= 8 && wid < 12) {
    float* Lp = lds + ((size_t)((wid - 8) * 64 + lane)) * 33;
#pragma unroll
    for (int k = 0; k < 32; ++k) Lp[k] += accA[k] - accB[k];
  }
  __syncthreads();
  if (wid >= 4 && wid < 8) {
    float* Lp = lds + ((size_t)((wid - 4) * 64 + lane)) * 33;
#pragma unroll
    for (int k = 0; k < 32; ++k) Lp[k] += accA[k] - accB[k];
  }
  __syncthreads();
  if (wid < 4) {
    float* Lp = lds + ((size_t)(wid * 64 + lane)) * 33;
#pragma unroll
    for (int k = 0; k < 32; ++k) Lp[k] += accA[k] - accB[k];
  }
  __syncthreads();
  // softmax phase: waves 0..7 (n = lane, kq = wid), waves 8..15 idle
  const int n = lane;
  const int kq = wid;
  float vals[4];
  float e[4];
  if (wid < 8) {
#pragma unroll
    for (int j = 0; j < 4; ++j) {
      const int k = kq * 4 + j;
      float s = 0.f;
#pragma unroll
      for (int g = 0; g < 4; ++g) s += lds[((size_t)(g * 64 + n)) * 33 + k];
      vals[j] = -0.5f * (s + t3[b * KK + k]);
    }
    float m4 = fmaxf(fmaxf(vals[0], vals[1]), fmaxf(vals[2], vals[3]));
    smax[n * 9 + kq] = m4;
  }
  __syncthreads();
  if (wid < 8) {
    float m = smax[n * 9 + 0];
#pragma unroll
    for (int g = 1; g < 8; ++g) m = fmaxf(m, smax[n * 9 + g]);
    float ps = 0.f;
#pragma unroll
    for (int j = 0; j < 4; ++j) {
      e[j] = __expf(vals[j] - m);
      ps += e[j];
    }
    ssum[n * 9 + kq] = ps;
  }
  __syncthreads();
  if (wid < 8) {
    float tot = 0.f;
#pragma unroll
    for (int g = 0; g < 8; ++g) tot += ssum[n * 9 + g];
    const float inv = 1.f / tot;
    float4 q4;
    q4.x = e[0] * inv; q4.y = e[1] * inv;
    q4.z = e[2] * inv; q4.w = e[3] * inv;
    *reinterpret_cast<float4*>(qout + ((size_t)b * NN + n0 + n) * KK + kq * 4) =
        q4;
    float qs[4] = {q4.x, q4.y, q4.z, q4.w};
#pragma unroll
    for (int j = 0; j < 4; ++j) {
      const float v = wredsum(qs[j]);
      if (n == 0) qpart[((size_t)b * KK + kq * 4 + j) * NT2 + tile] = v;
    }
  }
}

// Kernel 4: znq8[e][b][k][c] = sum_{n in eighth} x[c,n] * Q[b,n,k].
// Q in [b][n][k]: scalar loads coalesced over the 32 k lanes (proven pattern).
// grid = B*32ct*NE = 1024, block 256.
__global__ __launch_bounds__(256) void k_xp(const float* __restrict__ x,
                                            const float* __restrict__ p,
                                            float* __restrict__ outq) {
  const int e = blockIdx.x & 7;
  const int ct = (blockIdx.x >> 3) & 31;
  const int b = blockIdx.x >> 8;
  const int tid = threadIdx.x;
  const int k = tid & 31;
  const int g = tid >> 5;  // 8 n-groups of 64
  const int n0 = e * 512 + g * 64;
  const float* xb = x + (size_t)(b * CC + ct * 8) * NN;
  const float* pb = p + (size_t)b * NN * KK + k;
  float acc[8] = {0.f, 0.f, 0.f, 0.f, 0.f, 0.f, 0.f, 0.f};
  for (int n = n0; n < n0 + 64; n += 4) {
    const float p0 = pb[(size_t)(n + 0) * KK];
    const float p1 = pb[(size_t)(n + 1) * KK];
    const float p2 = pb[(size_t)(n + 2) * KK];
    const float p3 = pb[(size_t)(n + 3) * KK];
#pragma unroll
    for (int c = 0; c < 8; ++c) {
      const float4 xv = *reinterpret_cast<const float4*>(xb + (size_t)c * NN + n);
      acc[c] = fmaf(xv.x, p0, acc[c]);
      acc[c] = fmaf(xv.y, p1, acc[c]);
      acc[c] = fmaf(xv.z, p2, acc[c]);
      acc[c] = fmaf(xv.w, p3, acc[c]);
    }
  }
  __shared__ float lds[8 * 8 * 33];
#pragma unroll
  for (int c = 0; c < 8; ++c) lds[(g * 8 + c) * 33 + k] = acc[c];
  __syncthreads();
  const int c2 = tid & 7, k2 = tid >> 3;
  float s = 0.f;
#pragma unroll
  for (int gg = 0; gg < 8; ++gg) s += lds[(gg * 8 + c2) * 33 + k2];
  outq[((size_t)(e * BB + b) * KK + k2) * CC + ct * 8 + c2] = s;
}

// Kernel 5: Qsum reduce + Z = scale*(Znum/Qsum - code), d-normalized.
// grid = B*K, block 256.
__global__ __launch_bounds__(256) void k_z(const float* __restrict__ znq8,
                                           const float* __restrict__ code,
                                           const float* __restrict__ scale,
                                           const float* __restrict__ qpart,
                                           float* __restrict__ zout) {
  const int b = blockIdx.x >> 5;
  const int k = blockIdx.x & 31;
  const int d = threadIdx.x;
  __shared__ float rb[4];
  float qp = (d < NT2) ? qpart[((size_t)b * KK + k) * NT2 + d] : 0.f;
  qp = wredsum(qp);
  if ((d & 63) == 0) rb[d >> 6] = qp;
  __syncthreads();
  const float qs = rb[0] + rb[1] + rb[2] + rb[3];
  float zn = 0.f;
#pragma unroll
  for (int e = 0; e < NE; ++e)
    zn += znq8[((size_t)(e * BB + b) * KK + k) * CC + d];
  const float cd = code[((size_t)b * DD + d) * KK + k];
  const float z_ = scale[(size_t)d * KK + k] * (zn / qs - cd);
  float ss = wredsum(z_ * z_);
  __syncthreads();
  if ((d & 63) == 0) rb[d >> 6] = ss;
  __syncthreads();
  const float rn = 1.f / sqrtf(rb[0] + rb[1] + rb[2] + rb[3]);
  zout[((size_t)b * DD + d) * KK + k] = z_ * rn;
}

extern "C" void kernel_launch(void* const* d_in, const int* in_sizes, int n_in,
                              void* d_out, int out_size, void* d_ws,
                              size_t ws_size, hipStream_t stream) {
  const float* x = (const float*)d_in[0];
  const float* wth = (const float*)d_in[1];
  const float* wphi = (const float*)d_in[2];
  const float* scale = (const float*)d_in[3];
  float* out = (float*)d_out;
  float* zout = out;                         // B*D*K = 32768
  float* qout = out + (size_t)BB * DD * KK;  // B*N*K = 524288
  float* ws = (float*)d_ws;
  float* SpE = ws;                                  // 64*B*K   = 8192
  float* m1e = SpE + (size_t)NSL * BB * KK;         // 64*B*K*C = 2097152
  float* code = m1e + (size_t)NSL * BB * KK * CC;   // B*D*K    = 32768
  float* bc2 = code + (size_t)BB * DD * KK;         // B*D*K    = 32768
  float* s2g = bc2 + (size_t)BB * DD * KK;          // D*K      = 8192
  float* t3 = s2g + (size_t)DD * KK;                // B*K      = 128
  float* qpart = t3 + BB * KK;                      // B*K*64   = 8192
  float* znq8 = qpart + (size_t)BB * KK * NT2;      // 8*B*K*C  = 262144

  k_pm1<<<BB * NSL * 4, 256, 0, stream>>>(x, wphi, m1e, SpE);
  k_code<<<BB * KK, 256, 0, stream>>>(m1e, SpE, wth, scale, code, bc2, s2g, t3);
  k_dist<<<BB * NT2, 1024, 0, stream>>>(x, s2g, bc2, t3, qout, qpart);
  k_xp<<<BB * 32 * NE, 256, 0, stream>>>(x, qout, znq8);
  k_z<<<BB * KK, 256, 0, stream>>>(znq8, code, scale, qpart, zout);
}